// Round 3
// baseline (343.075 us; speedup 1.0000x reference)
//
#include <hip/hip_runtime.h>
#include <math.h>

// VectorQuantizer: x (32768,64) f32, codebook (8192,64) f32, start/end/use_sk ints.
// Outputs concat: x_q_st (2097152 f32) | loss (1 f32) | indices (32768 as f32 values).
//
// R12: amortized-latency rescue (worklist) + register-slot pass1.
//  vq_sc:    sc_k exact (pairwise-8 numpy replica, f32) + cb -> bf16 rows (K=64).
//  vq_pass1: 32x32x16 MFMA filter, block = 128 tokens x 2048 codes (quarter), 4 waves
//            x 32 tokens (acc = 64 regs -> 3 waves/SIMD). Per (token,quarter):
//            running local min + REGISTER sorted top-8 slots (mono-f16 key, static
//            bubble insert) -- no LDS minima table, no end scan. Records -> 32
//            transposed planes cand[(q*8+j)*NTOK + token] (coalesced). Overflow
//            marker (cid 0xFFFE) iff (cnt>8 && 8th-smallest <= thr): keep-8-smallest
//            contains ALL entries <= final thr unless that condition holds -> exact.
//  vq_rescue: 1024 blocks x 32 tokens. Phase A: 4 thr/token read 32 slots (plane-
//            coalesced), thr = min+WINDOW, push surviving chunks (~1.3/token) to an
//            LDS worklist (overflow -> bitmap -> serial cleanup, never in practice).
//            Phase B: waves consume items; per item ALL loads (x row, 32 cb rows via
//            2 lanes/code, sc) issue together -> ONE dependent round-trip; BIT-EXACT
//            R1 numpy-replica eval (pairwise-8, j0-3/j4-7 lane split, tt = s03+s47
//            via shfl_xor(.,1), IEEE-commutative); lex-min via LDS CAS. Phase C:
//            epilogue replicating the OLD loss tree EXACTLY (per-token 6x shfl_down,
//            per-4-token (s0+s1)+(s2+s3), partial[token>>2]).
// Exactness: each quarter's min chunk is always slot0 -> rescue thr = global chunk-
// min + WINDOW; ref argmin's chunk mv <= that (R6-validated budget + sc_max) -> its
// chunk is always evaluated; rescue evals every in-range code of surviving chunks
// with the exact arithmetic -> lex-min over a superset == reference.
// DO NOT change the exact-path arithmetic: inter-code d gaps are ~1 ulp of d.

#define N_E    8192
#define EDIM   64
#define NTOK   32768
#define NELEM  (NTOK * EDIM)
#define CSZ    32                  // chunk size
#define WINDOW 3e-4f
#define TTOK   128                 // pass-1 tokens per block
#define TCODE  2048                // pass-1 codes per block (16 iters of 128)
#define SROW   72                  // Cs stride (ushorts; 36 dwords == 4 mod 8)
#define TOKB   32                  // rescue tokens per block
#define WLCAP  512                 // rescue worklist capacity (expected ~42)

typedef __attribute__((ext_vector_type(8)))  short          short8;
typedef __attribute__((ext_vector_type(8)))  unsigned short ushort8v;
typedef __attribute__((ext_vector_type(16))) float          f32x16;

__device__ __forceinline__ unsigned short f2bf(float f) {   // RTNE f32->bf16 bits
  unsigned int u = __float_as_uint(f);
  return (unsigned short)((u + 0x7FFFu + ((u >> 16) & 1u)) >> 16);
}
__device__ __forceinline__ unsigned short f2h(float f) {
  union { _Float16 h; unsigned short u; } cv; cv.h = (_Float16)f; return cv.u;
}
__device__ __forceinline__ float h2f(unsigned short b) {
  union { _Float16 h; unsigned short u; } cv; cv.u = b; return (float)cv.h;
}
__device__ __forceinline__ float max16(const f32x16 a) {
  float m0 = fmaxf(fmaxf(a[0], a[1]),   fmaxf(a[2], a[3]));
  float m1 = fmaxf(fmaxf(a[4], a[5]),   fmaxf(a[6], a[7]));
  float m2 = fmaxf(fmaxf(a[8], a[9]),   fmaxf(a[10], a[11]));
  float m3 = fmaxf(fmaxf(a[12], a[13]), fmaxf(a[14], a[15]));
  return fmaxf(fmaxf(m0, m1), fmaxf(m2, m3));
}
// sx = np.sum(x*x) pairwise-8 replica (reads a 64-f32 row via float4*)
__device__ __forceinline__ float sx_of(const float4* xl4) {
#pragma clang fp contract(off)
  float a0=0,a1=0,a2=0,a3=0,a4=0,a5=0,a6=0,a7=0;
#pragma unroll
  for (int i = 0; i < 8; ++i) {
    float4 pA = xl4[2*i], pB = xl4[2*i+1];
    a0 += pA.x * pA.x; a1 += pA.y * pA.y; a2 += pA.z * pA.z; a3 += pA.w * pA.w;
    a4 += pB.x * pB.x; a5 += pB.y * pB.y; a6 += pB.z * pB.z; a7 += pB.w * pB.w;
  }
  return ((a0+a1) + (a2+a3)) + ((a4+a5) + (a6+a7));
}

// ---------------- sc (exact pairwise-8) + cb -> bf16 rows (K=64) --------------------
__global__ __launch_bounds__(256) void vq_sc(const float* __restrict__ cb,
                                             float* __restrict__ sc,
                                             unsigned short* __restrict__ cbf) {
#pragma clang fp contract(off)
  int r = blockIdx.x * 256 + threadIdx.x;
  const float4* c4 = (const float4*)(cb + (size_t)r * EDIM);
  float sval = sx_of(c4);
  sc[r] = sval;
  unsigned short* dst = cbf + (size_t)r * EDIM;
#pragma unroll
  for (int h = 0; h < 8; ++h) {
    float4 fA = c4[2*h], fB = c4[2*h+1];
    ushort8v o = {f2bf(fA.x), f2bf(fA.y), f2bf(fA.z), f2bf(fA.w),
                  f2bf(fB.x), f2bf(fB.y), f2bf(fB.z), f2bf(fB.w)};
    *(ushort8v*)&dst[h * 8] = o;
  }
}

// ---------------- pass 1: MFMA filter -> per-(token,quarter) candidate records ------
// Frags: A[m=lane&31][k=8*(lane>>5)+j] (codes), B same (tokens),
// D: col=lane&31 (token), row=(reg&3)+8*(reg>>2)+4*(lane>>5) (code).
__global__ __launch_bounds__(256, 3) void vq_pass1(
    const float* __restrict__ x, const unsigned short* __restrict__ cbf,
    unsigned int* __restrict__ cand,
    const int* __restrict__ p_start, const int* __restrict__ p_end) {
  __shared__ unsigned short Cs[128 * SROW];     // 18432 B
  int tid = threadIdx.x;
  int tb = blockIdx.x;    // token split [0,256)
  int cbk = blockIdx.y;   // code split  [0,4)  (the "quarter")
  int s = *p_start, e = *p_end;

  int lane = tid & 63, wv = tid >> 6;
  int half = lane >> 5, ln = lane & 31;
  int tokbase = wv * 32;

  // ---- stage first code tile: 128 rows x 8 ushort8 (linear, coalesced) ----
  const ushort8v* cg0 = (const ushort8v*)(cbf + (size_t)cbk * TCODE * EDIM);
#pragma unroll
  for (int p = 0; p < 4; ++p) {
    int idx = tid + p * 256;
    int row = idx >> 3, h = idx & 7;
    *(ushort8v*)&Cs[row * SROW + h * 8] = cg0[idx];
  }

  // ---- B fragments straight from global (fused f32 -> bf16) ----
  short8 bfr[4];
  {
    const float* xrow =
        x + (size_t)(tb * TTOK + tokbase + ln) * EDIM + half * 8;
#pragma unroll
    for (int ks = 0; ks < 4; ++ks) {
      float4 fA = *(const float4*)(xrow + ks * 16);
      float4 fB = *(const float4*)(xrow + ks * 16 + 4);
      short8 v = {(short)f2bf(fA.x), (short)f2bf(fA.y), (short)f2bf(fA.z),
                  (short)f2bf(fA.w), (short)f2bf(fB.x), (short)f2bf(fB.y),
                  (short)f2bf(fB.z), (short)f2bf(fB.w)};
      bfr[ks] = v;
    }
  }
  __syncthreads();

  // register sorted top-8 slots (ascending; key = mono-f16<<16 | local_chunk_id)
  unsigned s0=~0u,s1=~0u,s2=~0u,s3=~0u,s4=~0u,s5=~0u,s6=~0u,s7=~0u;
  float lminf = INFINITY;
  int cnt = 0;

  for (int nb = 0; nb < 16; ++nb) {
    ushort8v creg[4];
    if (nb < 15) {                               // prefetch next tile into registers
      const ushort8v* cg =
          (const ushort8v*)(cbf + ((size_t)cbk * TCODE + (nb + 1) * 128) * EDIM);
#pragma unroll
      for (int p = 0; p < 4; ++p) creg[p] = cg[tid + p * 256];
    }
    f32x16 acc[4];
#pragma unroll
    for (int ct = 0; ct < 4; ++ct) acc[ct] = (f32x16)0.0f;
#pragma unroll
    for (int ks = 0; ks < 4; ++ks)
#pragma unroll
      for (int ct = 0; ct < 4; ++ct) {
        short8 a = *(const short8*)&Cs[(ct*32 + ln) * SROW + ks*16 + half*8];
        acc[ct] = __builtin_amdgcn_mfma_f32_32x32x16_bf16(a, bfr[ks],
                                                          acc[ct], 0, 0, 0);
      }
    __syncthreads();                             // all Cs reads done
    if (nb < 15) {
#pragma unroll
      for (int p = 0; p < 4; ++p) {
        int idx = tid + p * 256;
        int row = idx >> 3, h = idx & 7;
        *(ushort8v*)&Cs[row * SROW + h * 8] = creg[p];
      }
    }
    // epilogue (registers only): per-chunk max -> f16 min -> running top-8
    int cbase0 = cbk * TCODE + nb * 128;
#pragma unroll
    for (int ct = 0; ct < 4; ++ct) {
      int c0 = cbase0 + ct * 32;
      bool full = (c0 >= s) && (c0 + 32 <= e);
      float v;
      if (full) {
        v = max16(acc[ct]);
      } else {
        v = -INFINITY;
#pragma unroll
        for (int r = 0; r < 16; ++r) {
          int code = c0 + (r & 3) + 8 * (r >> 2) + 4 * half;
          if (code >= s && code < e) v = fmaxf(v, acc[ct][r]);
        }
      }
      v = fmaxf(v, __shfl_xor(v, 32, 64));       // chunk max in f32 acc space
      unsigned short hh = f2h(-2.0f * v);        // f16 chunk minimum (record value)
      float mvf = h2f(hh);
      lminf = fminf(lminf, mvf);
      if (mvf <= lminf + WINDOW) {
        cnt++;
        unsigned mono = (unsigned)hh ^ ((hh & 0x8000u) ? 0xFFFFu : 0x8000u);
        unsigned p = (mono << 16) | (unsigned)(nb * 4 + ct);
        if (p < s7) {                            // static bubble insert (sorted asc)
#define INS_(S) { unsigned lo_ = (S) < p ? (S) : p; unsigned hi_ = (S) < p ? p : (S); (S) = lo_; p = hi_; }
          INS_(s0) INS_(s1) INS_(s2) INS_(s3) INS_(s4) INS_(s5) INS_(s6) INS_(s7)
#undef INS_
        }
      }
    }
    __syncthreads();                             // Cs writes visible before next MFMA
  }

  // ---- emit record: 8 slots to transposed planes (half==0 lanes; coalesced) ----
  if (!half) {
    float thr = lminf + WINDOW;
    unsigned rec[8];
#define EMIT_(J, S) { unsigned mono_ = (S) >> 16; \
    unsigned hh_ = (mono_ & 0x8000u) ? (mono_ ^ 0x8000u) : (mono_ ^ 0xFFFFu); \
    float v_ = h2f((unsigned short)hh_); \
    rec[J] = (v_ <= thr) ? ((hh_ << 16) | ((S) & 0xFFFFu)) : 0xFFFFFFFFu; }
    EMIT_(0, s0) EMIT_(1, s1) EMIT_(2, s2) EMIT_(3, s3)
    EMIT_(4, s4) EMIT_(5, s5) EMIT_(6, s6) EMIT_(7, s7)
#undef EMIT_
    {
      unsigned mono_ = s7 >> 16;
      unsigned hh_ = (mono_ & 0x8000u) ? (mono_ ^ 0x8000u) : (mono_ ^ 0xFFFFu);
      float v7 = h2f((unsigned short)hh_);
      if (cnt > 8 && v7 <= thr) rec[7] = 0x0000FFFEu;   // OVERFLOW marker
    }
    int token = tb * TTOK + tokbase + ln;
#pragma unroll
    for (int j = 0; j < 8; ++j)
      cand[(size_t)(cbk * 8 + j) * NTOK + token] = rec[j];
  }
}

// ---------------- pass 2: worklist rescue + epilogue --------------------------------
__global__ __launch_bounds__(256) void vq_rescue(
    const float* __restrict__ x, const float* __restrict__ cb,
    const float* __restrict__ sc, const unsigned int* __restrict__ cand,
    float* __restrict__ out_xq, float* __restrict__ out_idx,
    float* __restrict__ partial,
    const int* __restrict__ p_start, const int* __restrict__ p_end) {
#pragma clang fp contract(off)
  __shared__ unsigned wl[WLCAP];
  __shared__ unsigned long long best[TOKB];
  __shared__ float xrow[4][64];
  __shared__ int wlN, wpos;
  __shared__ unsigned ovbm;
  int tid  = threadIdx.x;
  int wv   = tid >> 6;
  int lane = tid & 63;
  int blk  = blockIdx.x;
  int s = *p_start, e = *p_end;

  if (tid < TOKB) best[tid] = ~0ull;
  if (tid == 0) { wlN = 0; wpos = 0; ovbm = 0; }
  __syncthreads();

  // ---- phase A: records -> thr -> worklist (4 threads/token, plane-coalesced) ----
  if (tid < 4 * TOKB) {
    int tl = tid >> 2, q = tid & 3;
    int gtok = blk * TOKB + tl;
    unsigned rv[8];
    float mv[8];
#pragma unroll
    for (int j = 0; j < 8; ++j) {
      rv[j] = cand[(size_t)(q * 8 + j) * NTOK + gtok];
      unsigned cid = rv[j] & 0xFFFFu;
      mv[j] = (cid < 64u) ? h2f((unsigned short)(rv[j] >> 16)) : INFINITY;
    }
    float m = INFINITY;
#pragma unroll
    for (int j = 0; j < 8; ++j) m = fminf(m, mv[j]);
    m = fminf(m, __shfl_xor(m, 1, 64));          // combine the token's 4 quarters
    m = fminf(m, __shfl_xor(m, 2, 64));
    float thr = m + WINDOW;
#pragma unroll
    for (int j = 0; j < 8; ++j) {
      unsigned cid = rv[j] & 0xFFFFu;
      unsigned ent = 0; bool push = false;
      if (cid < 64u) {
        if (mv[j] <= thr) { ent = ((unsigned)tl << 16) | (unsigned)(q * 64 + (int)cid); push = true; }
      } else if (cid == 0xFFFEu) {
        ent = ((unsigned)tl << 16) | 0x100u | (unsigned)q;  // full-quarter item
        push = true;
      }
      if (push) {
        int i = atomicAdd(&wlN, 1);
        if (i < WLCAP) wl[i] = ent;
        else atomicOr(&ovbm, 1u << tl);          // fallback (never in practice)
      }
    }
  }
  __syncthreads();
  int n = wlN; if (n > WLCAP) n = WLCAP;

  // exact per-chunk eval: 2 lanes/code, j0-3 / j4-7 split, BIT-EXACT R1 replica
#define EVAL_CHUNK(CH, SX, BP) do {                                            \
    int c_ = lane >> 1, h5_ = lane & 1;                                        \
    int k_ = (int)(CH) * CSZ + c_;                                             \
    const float4* c4_ = (const float4*)(cb + (size_t)k_ * EDIM);               \
    float t0_=0.0f,t1_=0.0f,t2_=0.0f,t3_=0.0f;                                 \
    _Pragma("unroll")                                                          \
    for (int i_ = 0; i_ < 8; ++i_) {             /* elements ascending i */    \
      float4 v_ = c4_[2*i_ + h5_];                                             \
      float4 p_ = xl4[2*i_ + h5_];                                             \
      t0_ += v_.x * p_.x; t1_ += v_.y * p_.y;                                  \
      t2_ += v_.z * p_.z; t3_ += v_.w * p_.w;                                  \
    }                                                                          \
    float s2_ = (t0_ + t1_) + (t2_ + t3_);       /* s03 (h5=0) / s47 (h5=1) */ \
    float tt_ = s2_ + __shfl_xor(s2_, 1, 64);    /* IEEE add commutative */    \
    if (k_ >= s && k_ < e) {                                                   \
      float d_ = ((SX) + sc[k_]) - 2.0f * tt_;                                 \
      unsigned db_ = __float_as_uint(d_);                                      \
      unsigned en_ = db_ ^ ((unsigned)((int)db_ >> 31) | 0x80000000u);         \
      unsigned long long pk_ = ((unsigned long long)en_ << 32) | (unsigned)k_; \
      if (pk_ < (BP)) (BP) = pk_;                                              \
    }                                                                          \
  } while (0)

#define CASMIN(TL, BP) do {                                                    \
    if (lane == 0 && (BP) != ~0ull) {                                          \
      unsigned long long cur_ = best[TL];                                      \
      while ((BP) < cur_) {                                                    \
        unsigned long long pr_ = atomicCAS(&best[TL], cur_, (BP));             \
        if (pr_ == cur_) break;                                                \
        cur_ = pr_;                                                            \
      }                                                                        \
    }                                                                          \
  } while (0)

  // ---- phase B: waves consume worklist items (batched loads, 1 round-trip) ----
  for (;;) {
    int idx = 0;
    if (lane == 0) idx = atomicAdd(&wpos, 1);
    idx = __shfl(idx, 0, 64);
    if (idx >= n) break;
    unsigned ent = wl[idx];
    int tl = (int)(ent >> 16);
    int gtok = blk * TOKB + tl;
    float xv = x[(size_t)gtok * EDIM + lane];
    xrow[wv][lane] = xv;                         // wave-private, in-order DS
    const float4* xl4 = (const float4*)xrow[wv];
    float sx = sx_of(xl4);
    unsigned long long bp = ~0ull;
    if (ent & 0x100u) {                          // full-quarter item (rare)
      int q = (int)(ent & 3u);
      for (int c2 = 0; c2 < 64; ++c2) EVAL_CHUNK(q * 64 + c2, sx, bp);
    } else {
      EVAL_CHUNK(ent & 0xFFu, sx, bp);
    }
#pragma unroll
    for (int off = 32; off >= 1; off >>= 1) {    // lex-min (d asc, k asc)
      unsigned long long o = __shfl_xor(bp, off, 64);
      if (o < bp) bp = o;
    }
    CASMIN(tl, bp);
  }
  __syncthreads();

  // ---- cleanup for worklist overflow (guaranteed-correct, never in practice) ----
  if (ovbm && wv == 0) {
    unsigned ov = ovbm;
    for (int tl = 0; tl < TOKB; ++tl) {
      if (!(ov & (1u << tl))) continue;
      int gtok = blk * TOKB + tl;
      unsigned rv = (lane < 32) ? cand[(size_t)lane * NTOK + gtok] : 0xFFFFFFFFu;
      unsigned cid = rv & 0xFFFFu;
      float mvf = (cid < 64u) ? h2f((unsigned short)(rv >> 16)) : INFINITY;
      float m = mvf;
#pragma unroll
      for (int off = 32; off >= 1; off >>= 1) m = fminf(m, __shfl_xor(m, off, 64));
      float thr = m + WINDOW;
      float xv = x[(size_t)gtok * EDIM + lane];
      xrow[0][lane] = xv;
      const float4* xl4 = (const float4*)xrow[0];
      float sx = sx_of(xl4);
      unsigned long long bp = ~0ull;
      int mych = ((lane >> 3) & 3) * 64 + (int)cid;
      unsigned long long bal = __ballot((lane < 32) && (cid < 64u) && (mvf <= thr));
      while (bal) {
        int b = __ffsll(bal) - 1; bal &= bal - 1;
        int ch = __shfl(mych, b, 64);
        EVAL_CHUNK(ch, sx, bp);
      }
      unsigned long long mb = __ballot((lane < 32) && (cid == 0xFFFEu));
      while (mb) {
        int b = __ffsll(mb) - 1; mb &= mb - 1;
        int q = (b >> 3) & 3;
        for (int c2 = 0; c2 < 64; ++c2) EVAL_CHUNK(q * 64 + c2, sx, bp);
      }
#pragma unroll
      for (int off = 32; off >= 1; off >>= 1) {
        unsigned long long o = __shfl_xor(bp, off, 64);
        if (o < bp) bp = o;
      }
      CASMIN(tl, bp);
    }
  }
  __syncthreads();
#undef EVAL_CHUNK
#undef CASMIN

  // ---- phase C: epilogue; EXACT replica of the legacy loss tree -----------------
  // wave wv handles groups {2wv, 2wv+1} of 4 tokens; partial[global_group] matches
  // the old per-4-token-block layout (vq_loss unchanged).
#pragma unroll
  for (int gi = 0; gi < 2; ++gi) {
    int gg = wv * 2 + gi;
    int t0 = gg * 4;
    int b0 = (int)(unsigned)(best[t0+0] & 0xFFFFFFFFull) & (N_E - 1);
    int b1 = (int)(unsigned)(best[t0+1] & 0xFFFFFFFFull) & (N_E - 1);
    int b2 = (int)(unsigned)(best[t0+2] & 0xFFFFFFFFull) & (N_E - 1);
    int b3 = (int)(unsigned)(best[t0+3] & 0xFFFFFFFFull) & (N_E - 1);
    size_t base = (size_t)(blk * TOKB + t0) * EDIM + lane;
    float xx0 = x[base], xx1 = x[base + EDIM], xx2 = x[base + 2*EDIM], xx3 = x[base + 3*EDIM];
    float qv0 = cb[(size_t)b0 * EDIM + lane];
    float qv1 = cb[(size_t)b1 * EDIM + lane];
    float qv2 = cb[(size_t)b2 * EDIM + lane];
    float qv3 = cb[(size_t)b3 * EDIM + lane];
    float sg0, sg1, sg2, sg3;
#define TOKEP(J, QV, XX, BI, SG) {                                             \
      float diff = (QV) - (XX);                       /* fl(x_q - x) */        \
      out_xq[base + (J) * EDIM] = (XX) + diff;        /* fl(x + fl(.)) */      \
      if (lane == 0) out_idx[blk * TOKB + t0 + (J)] = (float)(BI);             \
      float l = diff * diff;                                                   \
      _Pragma("unroll")                                                        \
      for (int off = 32; off >= 1; off >>= 1) l += __shfl_down(l, off, 64);    \
      SG = l; }
    TOKEP(0, qv0, xx0, b0, sg0)
    TOKEP(1, qv1, xx1, b1, sg1)
    TOKEP(2, qv2, xx2, b2, sg2)
    TOKEP(3, qv3, xx3, b3, sg3)
#undef TOKEP
    if (lane == 0)
      partial[blk * 8 + gg] = (sg0 + sg1) + (sg2 + sg3);
  }
}

// ---------------- final loss reduction ----------------------------------------------
__global__ __launch_bounds__(256) void vq_loss(const float* __restrict__ partial,
                                               float* __restrict__ out_loss) {
  int tid = threadIdx.x;
  float s = 0.0f;
  for (int i = tid; i < NTOK / 4; i += 256) s += partial[i];
#pragma unroll
  for (int off = 32; off >= 1; off >>= 1) s += __shfl_down(s, off, 64);
  __shared__ float sdata[4];
  if ((tid & 63) == 0) sdata[tid >> 6] = s;
  __syncthreads();
  if (tid == 0) {
    float total = (sdata[0] + sdata[1]) + (sdata[2] + sdata[3]);
    float m = total * (1.0f / (float)NELEM);
    out_loss[0] = m + 0.25f * m;
  }
}

// ---------------- launch -------------------------------------------------------------
extern "C" void kernel_launch(void* const* d_in, const int* in_sizes, int n_in,
                              void* d_out, int out_size, void* d_ws, size_t ws_size,
                              hipStream_t stream) {
  const float* x  = (const float*)d_in[0];
  const float* cb = (const float*)d_in[1];
  const int* p_start = (const int*)d_in[2];
  const int* p_end   = (const int*)d_in[3];

  float* ws = (float*)d_ws;
  float* sc      = ws;                                            // 8192 f
  float* partial = ws + N_E;                                      // 8192 f
  unsigned short* cbf  = (unsigned short*)(ws + 2 * N_E);         // 8192*64 us (1MB)
  unsigned int*   cand = (unsigned int*)(cbf + (size_t)N_E * EDIM); // 32 planes x NTOK u32 (4MB)

  float* out      = (float*)d_out;
  float* out_xq   = out;                 // 2097152
  float* out_loss = out + NELEM;         // 1
  float* out_idx  = out + NELEM + 1;     // 32768

  vq_sc<<<N_E / 256, 256, 0, stream>>>(cb, sc, cbf);
  dim3 g1(NTOK / TTOK, N_E / TCODE);
  vq_pass1<<<g1, 256, 0, stream>>>(x, cbf, cand, p_start, p_end);
  vq_rescue<<<NTOK / TOKB, 256, 0, stream>>>(x, cb, sc, cand, out_xq, out_idx,
                                             partial, p_start, p_end);
  vq_loss<<<1, 256, 0, stream>>>(partial, out_loss);
}

// Round 4
// 283.954 us; speedup vs baseline: 1.2082x; 1.2082x over previous
//
#include <hip/hip_runtime.h>
#include <math.h>

// VectorQuantizer: x (32768,64) f32, codebook (8192,64) f32, start/end/use_sk ints.
// Outputs concat: x_q_st (2097152 f32) | loss (1 f32) | indices (32768 as f32 values).
//
// R13: exact overflow marker + bitmap fallback; token-owned rescue (no worklist
// stealing, no CAS); x/sx staged once per token in LDS; 32 waves/CU rescue.
//  vq_sc:    sc_k exact (pairwise-8 numpy replica, f32) + cb -> bf16 rows (K=64).
//  vq_pass1: 32x32x16 MFMA filter, block = 128 tokens x 2048 codes (quarter).
//            Per (token,quarter): running local min, REGISTER sorted slots s0..s8
//            (mono-f16 key), and a 64-bit BITMAP of running-window accepts.
//            Emit: 8 slot planes (final-thr filtered) + 2 bitmap planes. Marker
//            (rec[7].cid=0xFFFE) iff mv(s8) <= thr_final -- EXACT condition for
//            ">=9 chunks within final local window" (R12's cnt>8 proxy fired on
//            stale running-window accepts -> 64-eval full-quarter items).
//            Bitmap is a superset of final-window chunks: accept test uses the
//            running min (>= final min), so every final-window chunk is accepted.
//  vq_rescue: 2048 blocks x 16 tokens x 4 waves (32 waves/CU). Phase A: wave0
//            reads slot planes -> per-token gthr = min+WINDOW -> per-token LDS
//            chunk lists (~2.6/token; marker quarters push bitmap bits); waves1-2
//            stage x rows to LDS; wave3 computes exact sx per token (serial
//            pairwise-8 replica). Phase B: wave wv OWNS tokens 4wv..4wv+3 (= one
//            legacy partial group): per token, eval listed chunks with the
//            BIT-EXACT R1 numpy-replica arithmetic (2 lanes/code, j0-3/j4-7
//            split, tt = s03+s47 via shfl_xor(.,1), IEEE-commutative), one
//            lex-min reduce, fused epilogue with the EXACT legacy loss tree
//            (per-token 6x shfl_down, (s0+s1)+(s2+s3), partial[token>>2]).
//            List overflow (>24, ~never) -> brute-force eval of all 256 chunks.
// Exactness: gthr = global chunk-min + WINDOW (slot0 always = local min). Ref
// argmin's chunk mv <= gthr (R6-validated budget + sc_max slack). Every chunk
// with mv <= gthr is in its quarter's slots (if among 8 smallest) or the marker
// fires and the bitmap contains it -> always pushed -> evaluated exactly ->
// lex-min over a superset containing the reference argmin == reference.
// DO NOT change the exact-path arithmetic: inter-code d gaps are ~1 ulp of d.

#define N_E    8192
#define EDIM   64
#define NTOK   32768
#define NELEM  (NTOK * EDIM)
#define CSZ    32                  // chunk size
#define WINDOW 3e-4f
#define TTOK   128                 // pass-1 tokens per block
#define TCODE  2048                // pass-1 codes per block (16 iters of 128)
#define SROW   72                  // Cs stride (ushorts; 36 dwords == 4 mod 8)
#define TOKB   16                  // rescue tokens per block
#define PCAP   24                  // rescue per-token list capacity

typedef __attribute__((ext_vector_type(8)))  short          short8;
typedef __attribute__((ext_vector_type(8)))  unsigned short ushort8v;
typedef __attribute__((ext_vector_type(16))) float          f32x16;

__device__ __forceinline__ unsigned short f2bf(float f) {   // RTNE f32->bf16 bits
  unsigned int u = __float_as_uint(f);
  return (unsigned short)((u + 0x7FFFu + ((u >> 16) & 1u)) >> 16);
}
__device__ __forceinline__ unsigned short f2h(float f) {
  union { _Float16 h; unsigned short u; } cv; cv.h = (_Float16)f; return cv.u;
}
__device__ __forceinline__ float h2f(unsigned short b) {
  union { _Float16 h; unsigned short u; } cv; cv.u = b; return (float)cv.h;
}
__device__ __forceinline__ float max16(const f32x16 a) {
  float m0 = fmaxf(fmaxf(a[0], a[1]),   fmaxf(a[2], a[3]));
  float m1 = fmaxf(fmaxf(a[4], a[5]),   fmaxf(a[6], a[7]));
  float m2 = fmaxf(fmaxf(a[8], a[9]),   fmaxf(a[10], a[11]));
  float m3 = fmaxf(fmaxf(a[12], a[13]), fmaxf(a[14], a[15]));
  return fmaxf(fmaxf(m0, m1), fmaxf(m2, m3));
}
// sx = np.sum(x*x) pairwise-8 replica (reads a 64-f32 row via float4*)
__device__ __forceinline__ float sx_of(const float4* xl4) {
#pragma clang fp contract(off)
  float a0=0,a1=0,a2=0,a3=0,a4=0,a5=0,a6=0,a7=0;
#pragma unroll
  for (int i = 0; i < 8; ++i) {
    float4 pA = xl4[2*i], pB = xl4[2*i+1];
    a0 += pA.x * pA.x; a1 += pA.y * pA.y; a2 += pA.z * pA.z; a3 += pA.w * pA.w;
    a4 += pB.x * pB.x; a5 += pB.y * pB.y; a6 += pB.z * pB.z; a7 += pB.w * pB.w;
  }
  return ((a0+a1) + (a2+a3)) + ((a4+a5) + (a6+a7));
}

// ---------------- sc (exact pairwise-8) + cb -> bf16 rows (K=64) --------------------
__global__ __launch_bounds__(256) void vq_sc(const float* __restrict__ cb,
                                             float* __restrict__ sc,
                                             unsigned short* __restrict__ cbf) {
#pragma clang fp contract(off)
  int r = blockIdx.x * 256 + threadIdx.x;
  const float4* c4 = (const float4*)(cb + (size_t)r * EDIM);
  float sval = sx_of(c4);
  sc[r] = sval;
  unsigned short* dst = cbf + (size_t)r * EDIM;
#pragma unroll
  for (int h = 0; h < 8; ++h) {
    float4 fA = c4[2*h], fB = c4[2*h+1];
    ushort8v o = {f2bf(fA.x), f2bf(fA.y), f2bf(fA.z), f2bf(fA.w),
                  f2bf(fB.x), f2bf(fB.y), f2bf(fB.z), f2bf(fB.w)};
    *(ushort8v*)&dst[h * 8] = o;
  }
}

// ---------------- pass 1: MFMA filter -> slots + bitmap per (token,quarter) ---------
// Frags: A[m=lane&31][k=8*(lane>>5)+j] (codes), B same (tokens),
// D: col=lane&31 (token), row=(reg&3)+8*(reg>>2)+4*(lane>>5) (code).
__global__ __launch_bounds__(256, 3) void vq_pass1(
    const float* __restrict__ x, const unsigned short* __restrict__ cbf,
    unsigned int* __restrict__ cand,
    const int* __restrict__ p_start, const int* __restrict__ p_end) {
  __shared__ unsigned short Cs[128 * SROW];     // 18432 B
  int tid = threadIdx.x;
  int tb = blockIdx.x;    // token split [0,256)
  int cbk = blockIdx.y;   // code split  [0,4)  (the "quarter")
  int s = *p_start, e = *p_end;

  int lane = tid & 63, wv = tid >> 6;
  int half = lane >> 5, ln = lane & 31;
  int tokbase = wv * 32;

  // ---- stage first code tile: 128 rows x 8 ushort8 (linear, coalesced) ----
  const ushort8v* cg0 = (const ushort8v*)(cbf + (size_t)cbk * TCODE * EDIM);
#pragma unroll
  for (int p = 0; p < 4; ++p) {
    int idx = tid + p * 256;
    int row = idx >> 3, h = idx & 7;
    *(ushort8v*)&Cs[row * SROW + h * 8] = cg0[idx];
  }

  // ---- B fragments straight from global (fused f32 -> bf16) ----
  short8 bfr[4];
  {
    const float* xrow =
        x + (size_t)(tb * TTOK + tokbase + ln) * EDIM + half * 8;
#pragma unroll
    for (int ks = 0; ks < 4; ++ks) {
      float4 fA = *(const float4*)(xrow + ks * 16);
      float4 fB = *(const float4*)(xrow + ks * 16 + 4);
      short8 v = {(short)f2bf(fA.x), (short)f2bf(fA.y), (short)f2bf(fA.z),
                  (short)f2bf(fA.w), (short)f2bf(fB.x), (short)f2bf(fB.y),
                  (short)f2bf(fB.z), (short)f2bf(fB.w)};
      bfr[ks] = v;
    }
  }
  __syncthreads();

  // register sorted slots s0..s8 (ascending; key = mono-f16<<16 | local_chunk_id)
  // + 64-bit bitmap of running-window accepts
  unsigned s0=~0u,s1=~0u,s2=~0u,s3=~0u,s4=~0u,s5=~0u,s6=~0u,s7=~0u,s8=~0u;
  unsigned long long bmap = 0ull;
  float lminf = INFINITY;

  for (int nb = 0; nb < 16; ++nb) {
    ushort8v creg[4];
    if (nb < 15) {                               // prefetch next tile into registers
      const ushort8v* cg =
          (const ushort8v*)(cbf + ((size_t)cbk * TCODE + (nb + 1) * 128) * EDIM);
#pragma unroll
      for (int p = 0; p < 4; ++p) creg[p] = cg[tid + p * 256];
    }
    f32x16 acc[4];
#pragma unroll
    for (int ct = 0; ct < 4; ++ct) acc[ct] = (f32x16)0.0f;
#pragma unroll
    for (int ks = 0; ks < 4; ++ks)
#pragma unroll
      for (int ct = 0; ct < 4; ++ct) {
        short8 a = *(const short8*)&Cs[(ct*32 + ln) * SROW + ks*16 + half*8];
        acc[ct] = __builtin_amdgcn_mfma_f32_32x32x16_bf16(a, bfr[ks],
                                                          acc[ct], 0, 0, 0);
      }
    __syncthreads();                             // all Cs reads done
    if (nb < 15) {
#pragma unroll
      for (int p = 0; p < 4; ++p) {
        int idx = tid + p * 256;
        int row = idx >> 3, h = idx & 7;
        *(ushort8v*)&Cs[row * SROW + h * 8] = creg[p];
      }
    }
    // epilogue (registers only): per-chunk max -> f16 min -> running slots/bitmap
    int cbase0 = cbk * TCODE + nb * 128;
#pragma unroll
    for (int ct = 0; ct < 4; ++ct) {
      int c0 = cbase0 + ct * 32;
      bool full = (c0 >= s) && (c0 + 32 <= e);
      float v;
      if (full) {
        v = max16(acc[ct]);
      } else {
        v = -INFINITY;
#pragma unroll
        for (int r = 0; r < 16; ++r) {
          int code = c0 + (r & 3) + 8 * (r >> 2) + 4 * half;
          if (code >= s && code < e) v = fmaxf(v, acc[ct][r]);
        }
      }
      v = fmaxf(v, __shfl_xor(v, 32, 64));       // chunk max in f32 acc space
      unsigned short hh = f2h(-2.0f * v);        // f16 chunk minimum (record value)
      float mvf = h2f(hh);
      lminf = fminf(lminf, mvf);
      if (mvf <= lminf + WINDOW) {               // running-window accept
        bmap |= 1ull << (nb * 4 + ct);
        unsigned mono = (unsigned)hh ^ ((hh & 0x8000u) ? 0xFFFFu : 0x8000u);
        unsigned p = (mono << 16) | (unsigned)(nb * 4 + ct);
        if (p < s8) {                            // static bubble insert (sorted asc)
#define INS_(S) { unsigned lo_ = (S) < p ? (S) : p; unsigned hi_ = (S) < p ? p : (S); (S) = lo_; p = hi_; }
          INS_(s0) INS_(s1) INS_(s2) INS_(s3) INS_(s4) INS_(s5) INS_(s6) INS_(s7) INS_(s8)
#undef INS_
        }
      }
    }
    __syncthreads();                             // Cs writes visible before next MFMA
  }

  // ---- emit record: 8 slot planes + 2 bitmap planes (half==0 lanes; coalesced) ----
  if (!half) {
    float thr = lminf + WINDOW;
    unsigned rec[8];
#define EMIT_(J, S) { unsigned mono_ = (S) >> 16; \
    unsigned hh_ = (mono_ & 0x8000u) ? (mono_ ^ 0x8000u) : (mono_ ^ 0xFFFFu); \
    float v_ = h2f((unsigned short)hh_); \
    rec[J] = (v_ <= thr) ? ((hh_ << 16) | ((S) & 0xFFFFu)) : 0xFFFFFFFFu; }
    EMIT_(0, s0) EMIT_(1, s1) EMIT_(2, s2) EMIT_(3, s3)
    EMIT_(4, s4) EMIT_(5, s5) EMIT_(6, s6) EMIT_(7, s7)
#undef EMIT_
    {
      unsigned mono_ = s8 >> 16;
      unsigned hh_ = (mono_ & 0x8000u) ? (mono_ ^ 0x8000u) : (mono_ ^ 0xFFFFu);
      float v8 = h2f((unsigned short)hh_);       // NaN when <9 accepts -> false
      if (v8 <= thr) rec[7] = 0x0000FFFEu;       // EXACT overflow marker
    }
    int token = tb * TTOK + tokbase + ln;
#pragma unroll
    for (int j = 0; j < 8; ++j)
      cand[(size_t)(cbk * 8 + j) * NTOK + token] = rec[j];
    cand[(size_t)(32 + cbk * 2) * NTOK + token] = (unsigned)(bmap & 0xFFFFFFFFull);
    cand[(size_t)(33 + cbk * 2) * NTOK + token] = (unsigned)(bmap >> 32);
  }
}

// ---------------- pass 2: token-owned rescue + fused epilogue -----------------------
__global__ __launch_bounds__(256) void vq_rescue(
    const float* __restrict__ x, const float* __restrict__ cb,
    const float* __restrict__ sc, const unsigned int* __restrict__ cand,
    float* __restrict__ out_xq, float* __restrict__ out_idx,
    float* __restrict__ partial,
    const int* __restrict__ p_start, const int* __restrict__ p_end) {
#pragma clang fp contract(off)
  __shared__ float xsh[TOKB][64];                 // 4 KB staged x rows
  __shared__ float sxs[TOKB];                     // exact sx per token
  __shared__ unsigned short lst[TOKB][PCAP];      // per-token chunk lists
  __shared__ int lcnt[TOKB];
  __shared__ unsigned bfflag;
  int tid  = threadIdx.x;
  int wv   = tid >> 6;
  int lane = tid & 63;
  int blk  = blockIdx.x;
  int s = *p_start, e = *p_end;

  if (tid < TOKB) lcnt[tid] = 0;
  if (tid == 0) bfflag = 0u;
  __syncthreads();

  // ---- phase A (split across waves; one barrier) --------------------------------
  if (tid < 64) {
    // wave 0: slot planes -> per-token gthr -> per-token chunk list
    int tl = tid >> 2, q = tid & 3;
    int gtok = blk * TOKB + tl;
    unsigned rv[8];
#pragma unroll
    for (int j = 0; j < 8; ++j)
      rv[j] = cand[(size_t)(q * 8 + j) * NTOK + gtok];
    float m = INFINITY;
#pragma unroll
    for (int j = 0; j < 8; ++j) {
      unsigned cid = rv[j] & 0xFFFFu;
      float v = (cid < 64u) ? h2f((unsigned short)(rv[j] >> 16)) : INFINITY;
      m = fminf(m, v);
    }
    m = fminf(m, __shfl_xor(m, 1, 64));          // combine the token's 4 quarters
    m = fminf(m, __shfl_xor(m, 2, 64));
    float thr = m + WINDOW;                      // global window threshold
    bool marker = ((rv[7] & 0xFFFFu) == 0xFFFEu);
    if (!marker) {
#pragma unroll
      for (int j = 0; j < 8; ++j) {
        unsigned cid = rv[j] & 0xFFFFu;
        if (cid < 64u && h2f((unsigned short)(rv[j] >> 16)) <= thr) {
          int i = atomicAdd(&lcnt[tl], 1);
          if (i < PCAP) lst[tl][i] = (unsigned short)(q * 64 + (int)cid);
          else atomicOr(&bfflag, 1u << tl);
        }
      }
    } else {
      unsigned cid0 = rv[0] & 0xFFFFu;           // slot0 = quarter-local min
      float v0 = (cid0 < 64u) ? h2f((unsigned short)(rv[0] >> 16)) : INFINITY;
      if (v0 <= thr) {                           // quarter can contain survivors
        unsigned b0 = cand[(size_t)(32 + q * 2) * NTOK + gtok];
        unsigned b1 = cand[(size_t)(33 + q * 2) * NTOK + gtok];
        while (b0) { int j = __ffs(b0) - 1; b0 &= b0 - 1;
          int i = atomicAdd(&lcnt[tl], 1);
          if (i < PCAP) lst[tl][i] = (unsigned short)(q * 64 + j);
          else atomicOr(&bfflag, 1u << tl); }
        while (b1) { int j = __ffs(b1) - 1; b1 &= b1 - 1;
          int i = atomicAdd(&lcnt[tl], 1);
          if (i < PCAP) lst[tl][i] = (unsigned short)(q * 64 + 32 + j);
          else atomicOr(&bfflag, 1u << tl); }
      }
    }
  } else if (tid < 192) {
    // waves 1-2: stage x rows (coalesced: 8 threads x 32B per 256B row)
    int t = tid - 64;
    int tl = t >> 3, seg = t & 7;
    const float4* xg = (const float4*)(x + (size_t)(blk * TOKB + tl) * EDIM + seg * 8);
    float4 A = xg[0], B = xg[1];
    *(float4*)&xsh[tl][seg * 8]     = A;
    *(float4*)&xsh[tl][seg * 8 + 4] = B;
  } else if (tid < 192 + TOKB) {
    // wave 3: exact sx per token (serial pairwise-8 replica, from global)
    int tl = tid - 192;
    sxs[tl] = sx_of((const float4*)(x + (size_t)(blk * TOKB + tl) * EDIM));
  }
  __syncthreads();

  // exact per-chunk eval: 2 lanes/code, j0-3 / j4-7 split, BIT-EXACT R1 replica
#define EVAL_CHUNK(CH, XL4, SX, BP) do {                                       \
    int c_ = lane >> 1, h5_ = lane & 1;                                        \
    int k_ = (int)(CH) * CSZ + c_;                                             \
    const float4* c4_ = (const float4*)(cb + (size_t)k_ * EDIM);               \
    float t0_=0.0f,t1_=0.0f,t2_=0.0f,t3_=0.0f;                                 \
    _Pragma("unroll")                                                          \
    for (int i_ = 0; i_ < 8; ++i_) {             /* elements ascending i */    \
      float4 v_ = c4_[2*i_ + h5_];                                             \
      float4 p_ = (XL4)[2*i_ + h5_];                                           \
      t0_ += v_.x * p_.x; t1_ += v_.y * p_.y;                                  \
      t2_ += v_.z * p_.z; t3_ += v_.w * p_.w;                                  \
    }                                                                          \
    float s2_ = (t0_ + t1_) + (t2_ + t3_);       /* s03 (h5=0) / s47 (h5=1) */ \
    float tt_ = s2_ + __shfl_xor(s2_, 1, 64);    /* IEEE add commutative */    \
    if (k_ >= s && k_ < e) {                                                   \
      float d_ = ((SX) + sc[k_]) - 2.0f * tt_;                                 \
      unsigned db_ = __float_as_uint(d_);                                      \
      unsigned en_ = db_ ^ ((unsigned)((int)db_ >> 31) | 0x80000000u);         \
      unsigned long long pk_ = ((unsigned long long)en_ << 32) | (unsigned)k_; \
      if (pk_ < (BP)) (BP) = pk_;                                              \
    }                                                                          \
  } while (0)

  // ---- phase B: wave wv owns tokens 4wv..4wv+3 (= one legacy partial group) -----
  float sg[4];
#pragma unroll
  for (int ti = 0; ti < 4; ++ti) {
    int tl = wv * 4 + ti;
    int gtok = blk * TOKB + tl;
    const float4* xl4 = (const float4*)xsh[tl];
    float sx = sxs[tl];
    unsigned long long bp = ~0ull;
    if ((bfflag >> tl) & 1u) {                   // list overflow (~never): brute force
      for (int ch = 0; ch < 256; ++ch) EVAL_CHUNK(ch, xl4, sx, bp);
    } else {
      int n = lcnt[tl]; if (n > PCAP) n = PCAP;
      for (int i = 0; i < n; ++i) EVAL_CHUNK(lst[tl][i], xl4, sx, bp);
    }
#pragma unroll
    for (int off = 32; off >= 1; off >>= 1) {    // lex-min (d asc, k asc)
      unsigned long long o = __shfl_xor(bp, off, 64);
      if (o < bp) bp = o;
    }
    int bidx = (int)(unsigned)(bp & 0xFFFFFFFFull) & (N_E - 1);

    float xx = xsh[tl][lane];
    float qv = cb[(size_t)bidx * EDIM + lane];
    float diff = qv - xx;                              // fl(x_q - x)
    out_xq[(size_t)gtok * EDIM + lane] = xx + diff;    // fl(x + fl(x_q - x))
    if (lane == 0) out_idx[gtok] = (float)bidx;
    float l = diff * diff;
#pragma unroll
    for (int off = 32; off >= 1; off >>= 1) l += __shfl_down(l, off, 64);
    sg[ti] = l;                                  // legacy per-token tree
  }
#undef EVAL_CHUNK
  if (lane == 0)
    partial[blk * 4 + wv] = (sg[0] + sg[1]) + (sg[2] + sg[3]);
}

// ---------------- final loss reduction ----------------------------------------------
__global__ __launch_bounds__(256) void vq_loss(const float* __restrict__ partial,
                                               float* __restrict__ out_loss) {
  int tid = threadIdx.x;
  float s = 0.0f;
  for (int i = tid; i < NTOK / 4; i += 256) s += partial[i];
#pragma unroll
  for (int off = 32; off >= 1; off >>= 1) s += __shfl_down(s, off, 64);
  __shared__ float sdata[4];
  if ((tid & 63) == 0) sdata[tid >> 6] = s;
  __syncthreads();
  if (tid == 0) {
    float total = (sdata[0] + sdata[1]) + (sdata[2] + sdata[3]);
    float m = total * (1.0f / (float)NELEM);
    out_loss[0] = m + 0.25f * m;
  }
}

// ---------------- launch -------------------------------------------------------------
extern "C" void kernel_launch(void* const* d_in, const int* in_sizes, int n_in,
                              void* d_out, int out_size, void* d_ws, size_t ws_size,
                              hipStream_t stream) {
  const float* x  = (const float*)d_in[0];
  const float* cb = (const float*)d_in[1];
  const int* p_start = (const int*)d_in[2];
  const int* p_end   = (const int*)d_in[3];

  float* ws = (float*)d_ws;
  float* sc      = ws;                                            // 8192 f
  float* partial = ws + N_E;                                      // 8192 f
  unsigned short* cbf  = (unsigned short*)(ws + 2 * N_E);         // 8192*64 us (1MB)
  unsigned int*   cand = (unsigned int*)(cbf + (size_t)N_E * EDIM); // 40 planes x NTOK u32 (5.25MB)

  float* out      = (float*)d_out;
  float* out_xq   = out;                 // 2097152
  float* out_loss = out + NELEM;         // 1
  float* out_idx  = out + NELEM + 1;     // 32768

  vq_sc<<<N_E / 256, 256, 0, stream>>>(cb, sc, cbf);
  dim3 g1(NTOK / TTOK, N_E / TCODE);
  vq_pass1<<<g1, 256, 0, stream>>>(x, cbf, cand, p_start, p_end);
  vq_rescue<<<NTOK / TOKB, 256, 0, stream>>>(x, cb, sc, cand, out_xq, out_idx,
                                             partial, p_start, p_end);
  vq_loss<<<1, 256, 0, stream>>>(partial, out_loss);
}